// Round 3
// baseline (118.227 us; speedup 1.0000x reference)
//
#include <hip/hip_runtime.h>
#include <hip/hip_bf16.h>
#include <math.h>

#define TPB 64

// D = Za @ J @ Zb @ J @ Zc, where Z are the reference's z-rot matrices:
// Z[i][i] = cs[i], Z[i][DIM-1-i] = sn[i] (center row: cs=1, sn=0).
template<int DIM>
__device__ __forceinline__ void zchain(
    const float* __restrict__ J,
    const float (&ca)[DIM], const float (&sa)[DIM],
    const float (&cb)[DIM], const float (&sb)[DIM],
    const float (&cc)[DIM], const float (&sc)[DIM],
    float (&D)[DIM][DIM])
{
    constexpr int d1 = DIM - 1;
    float Jl[DIM][DIM];
#pragma unroll
    for (int i = 0; i < DIM; ++i)
#pragma unroll
        for (int j = 0; j < DIM; ++j)
            Jl[i][j] = J[i * DIM + j];   // uniform -> scalar loads

    float U[DIM][DIM];
#pragma unroll
    for (int i = 0; i < DIM; ++i)
#pragma unroll
        for (int j = 0; j < DIM; ++j)
            U[i][j] = ca[i] * Jl[i][j] + sa[i] * Jl[d1 - i][j];     // Za @ J

    float V[DIM][DIM];
#pragma unroll
    for (int i = 0; i < DIM; ++i)
#pragma unroll
        for (int j = 0; j < DIM; ++j)
            V[i][j] = U[i][j] * cb[j] + U[i][d1 - j] * sb[d1 - j];  // (.) @ Zb

    float W[DIM][DIM];
#pragma unroll
    for (int i = 0; i < DIM; ++i)
#pragma unroll
        for (int j = 0; j < DIM; ++j) {
            float acc = 0.f;
#pragma unroll
            for (int k = 0; k < DIM; ++k)
                acc = fmaf(V[i][k], Jl[k][j], acc);                 // (.) @ J
            W[i][j] = acc;
        }
#pragma unroll
    for (int i = 0; i < DIM; ++i)
#pragma unroll
        for (int j = 0; j < DIM; ++j)
            D[i][j] = W[i][j] * cc[j] + W[i][d1 - j] * sc[d1 - j];  // (.) @ Zc
}

__global__ __launch_bounds__(TPB) void wigner_kernel(
    const float* __restrict__ vec, const float* __restrict__ rnd,
    const float* __restrict__ J1,  const float* __restrict__ J2,
    const float* __restrict__ tom,
    float* __restrict__ outR,
    float* __restrict__ outWm,
    float* __restrict__ outWi,
    int E)
{
    __shared__ __align__(16) float lds[TPB * 81];
    __shared__ int invp[9];   // invp[W_row] = wm_row

    const int t  = threadIdx.x;
    const int e0 = blockIdx.x * TPB;
    const int e  = e0 + t;
    const int ei = (e < E) ? e : (E - 1);
    const int nvalid = min(TPB, E - e0);

    if (t < 9) {
        int p = 0;
#pragma unroll
        for (int k = 0; k < 9; ++k)
            if (tom[t * 9 + k] > 0.5f) p = k;   // to_m is a permutation matrix
        invp[p] = t;
    }

    // ---------------- per-edge math (f32) ----------------
    float vx = vec[3 * ei + 0], vy = vec[3 * ei + 1], vz = vec[3 * ei + 2];
    float rn = rsqrtf(vx * vx + vy * vy + vz * vz);
    float nx0 = vx * rn, nx1 = vy * rn, nx2 = vz * rn;     // norm_x

    float ox = rnd[3 * ei + 0] - 0.5f;
    float oy = rnd[3 * ei + 1] - 0.5f;
    float oz = rnd[3 * ei + 2] - 0.5f;
    float ro = rsqrtf(ox * ox + oy * oy + oz * oz);
    ox *= ro; oy *= ro; oz *= ro;                          // original e2

    // candidate selection (e2b, e2c built from ORIGINAL e2)
    float sx = ox, sy = oy, sz = oz;
    float dcur = fabsf(sx * nx0 + sy * nx1 + sz * nx2);
    {
        float bx = -oy, by = ox, bz = oz;
        float db = fabsf(bx * nx0 + by * nx1 + bz * nx2);
        if (dcur > db) { sx = bx; sy = by; sz = bz; dcur = db; }
        float cx = ox, cy = -oz, cz = oy;
        float dc = fabsf(cx * nx0 + cy * nx1 + cz * nx2);
        if (dcur > dc) { sx = cx; sy = cy; sz = cz; }
    }

    // norm_z = normalize(cross(norm_x, e2))
    float zx = nx1 * sz - nx2 * sy;
    float zy = nx2 * sx - nx0 * sz;
    float zz = nx0 * sy - nx1 * sx;
    float rz = rsqrtf(zx * zx + zy * zy + zz * zz);
    zx *= rz; zy *= rz; zz *= rz;

    // norm_y = normalize(cross(norm_x, norm_z))
    float yx = nx1 * zz - nx2 * zy;
    float yy = nx2 * zx - nx0 * zz;
    float yz = nx0 * zy - nx1 * zx;
    float ry = rsqrtf(yx * yx + yy * yy + yz * yz);
    yx *= ry; yy *= ry; yz *= ry;

    // R rows: [norm_z; norm_x; norm_y].  x = R[:, :, 1] = (zy, nx1, yy)
    float alpha = atan2f(zy, yy);
    float beta  = acosf(fminf(1.f, fmaxf(-1.f, nx1)));
    float sa, caa, sb, cbb, sg, cgg;
    sincosf(alpha, &sa, &caa);
    sincosf(beta,  &sb, &cbb);
    // Rg[0][j] = ca*R[0][j] - sa*R[2][j]; gamma = atan2(Rg[0][2], Rg[0][0])
    float gamma = atan2f(caa * zz - sa * yz, caa * zx - sa * yx);
    sincosf(gamma, &sg, &cgg);

    // l = 1 block
    float ca3[3] = {caa, 1.f, caa}, sa3[3] = {sa, 0.f, -sa};
    float cb3[3] = {cbb, 1.f, cbb}, sb3[3] = {sb, 0.f, -sb};
    float cc3[3] = {cgg, 1.f, cgg}, sc3[3] = {sg, 0.f, -sg};
    float D1[3][3];
    zchain<3>(J1, ca3, sa3, cb3, sb3, cc3, sc3, D1);

    // l = 2 block (double angles via identities; f32 precision, threshold 0.27 is generous)
    float ca2 = caa * caa - sa * sa,  sa2 = 2.f * sa * caa;
    float cb2 = cbb * cbb - sb * sb,  sb2 = 2.f * sb * cbb;
    float cg2 = cgg * cgg - sg * sg,  sg2 = 2.f * sg * cgg;
    float ca5[5] = {ca2, caa, 1.f, caa, ca2}, sa5[5] = {sa2, sa, 0.f, -sa, -sa2};
    float cb5[5] = {cb2, cbb, 1.f, cbb, cb2}, sb5[5] = {sb2, sb, 0.f, -sb, -sb2};
    float cc5[5] = {cg2, cgg, 1.f, cgg, cg2}, sc5[5] = {sg2, sg, 0.f, -sg, -sg2};
    float D2[5][5];
    zchain<5>(J2, ca5, sa5, cb5, sb5, cc5, sc5, D2);

    // ---------------- phase 1: R ----------------
    {
        float* r9 = &lds[t * 9];
        r9[0] = zx;  r9[1] = zy;  r9[2] = zz;
        r9[3] = nx0; r9[4] = nx1; r9[5] = nx2;
        r9[6] = yx;  r9[7] = yy;  r9[8] = yz;
    }
    __syncthreads();
    if (nvalid == TPB) {
        const float4* s4 = reinterpret_cast<const float4*>(lds);
        float4* d4 = reinterpret_cast<float4*>(outR + (size_t)e0 * 9);
        for (int idx = t; idx < (TPB * 9) / 4; idx += TPB) d4[idx] = s4[idx];
    } else {
        float* d = outR + (size_t)e0 * 9;
        for (int idx = t; idx < nvalid * 9; idx += TPB) d[idx] = lds[idx];
    }
    __syncthreads();

    // ---------------- phase 2: wm  (scatter W row r -> row invp[r]) ----------------
    {
        float* w = &lds[t * 81];
#pragma unroll
        for (int k = 0; k < 81; ++k) w[k] = 0.f;
        w[invp[0] * 9 + 0] = 1.f;
#pragma unroll
        for (int r = 0; r < 3; ++r) {
            int m = invp[1 + r];
#pragma unroll
            for (int c = 0; c < 3; ++c)
                w[m * 9 + (1 + c)] = D1[r][c];
        }
#pragma unroll
        for (int r = 0; r < 5; ++r) {
            int m = invp[4 + r];
#pragma unroll
            for (int c = 0; c < 5; ++c)
                w[m * 9 + (4 + c)] = D2[r][c];
        }
    }
    __syncthreads();
    if (nvalid == TPB) {
        const float4* s4 = reinterpret_cast<const float4*>(lds);
        float4* d4 = reinterpret_cast<float4*>(outWm + (size_t)e0 * 81);
        for (int idx = t; idx < (TPB * 81) / 4; idx += TPB) d4[idx] = s4[idx];
    } else {
        float* d = outWm + (size_t)e0 * 81;
        for (int idx = t; idx < nvalid * 81; idx += TPB) d[idx] = lds[idx];
    }
    __syncthreads();

    // ---------------- phase 3: wm_inv = wm^T per edge ----------------
    {
        float* w = &lds[t * 81];
#pragma unroll
        for (int k = 0; k < 81; ++k) w[k] = 0.f;
        w[0 * 9 + invp[0]] = 1.f;
#pragma unroll
        for (int r = 0; r < 3; ++r) {
            int m = invp[1 + r];
#pragma unroll
            for (int c = 0; c < 3; ++c)
                w[(1 + c) * 9 + m] = D1[r][c];
        }
#pragma unroll
        for (int r = 0; r < 5; ++r) {
            int m = invp[4 + r];
#pragma unroll
            for (int c = 0; c < 5; ++c)
                w[(4 + c) * 9 + m] = D2[r][c];
        }
    }
    __syncthreads();
    if (nvalid == TPB) {
        const float4* s4 = reinterpret_cast<const float4*>(lds);
        float4* d4 = reinterpret_cast<float4*>(outWi + (size_t)e0 * 81);
        for (int idx = t; idx < (TPB * 81) / 4; idx += TPB) d4[idx] = s4[idx];
    } else {
        float* d = outWi + (size_t)e0 * 81;
        for (int idx = t; idx < nvalid * 81; idx += TPB) d[idx] = lds[idx];
    }
}

extern "C" void kernel_launch(void* const* d_in, const int* in_sizes, int n_in,
                              void* d_out, int out_size, void* d_ws, size_t ws_size,
                              hipStream_t stream) {
    const float* vec = (const float*)d_in[0];
    const float* rnd = (const float*)d_in[1];
    const float* J1  = (const float*)d_in[2];
    const float* J2  = (const float*)d_in[3];
    const float* tom = (const float*)d_in[4];
    float* out = (float*)d_out;

    const int E = in_sizes[0] / 3;
    float* outR  = out;
    float* outWm = out + (size_t)E * 9;
    float* outWi = out + (size_t)E * 90;

    const int blocks = (E + TPB - 1) / TPB;
    hipLaunchKernelGGL(wigner_kernel, dim3(blocks), dim3(TPB), 0, stream,
                       vec, rnd, J1, J2, tom, outR, outWm, outWi, E);
}

// Round 5
// 108.355 us; speedup vs baseline: 1.0911x; 1.0911x over previous
//
#include <hip/hip_runtime.h>
#include <hip/hip_bf16.h>
#include <math.h>

#define TPB 64

typedef float f32x4 __attribute__((ext_vector_type(4)));

// D = Za @ J @ Zb @ J @ Zc  (reference z-rot structure: Z[i][i]=cs[i], Z[i][DIM-1-i]=sn[i])
template<int DIM>
__device__ __forceinline__ void zchain(
    const float* __restrict__ J,
    const float (&ca)[DIM], const float (&sa)[DIM],
    const float (&cb)[DIM], const float (&sb)[DIM],
    const float (&cc)[DIM], const float (&sc)[DIM],
    float (&D)[DIM][DIM])
{
    constexpr int d1 = DIM - 1;
    float Jl[DIM][DIM];
#pragma unroll
    for (int i = 0; i < DIM; ++i)
#pragma unroll
        for (int j = 0; j < DIM; ++j)
            Jl[i][j] = J[i * DIM + j];   // uniform -> scalar loads

    float U[DIM][DIM];
#pragma unroll
    for (int i = 0; i < DIM; ++i)
#pragma unroll
        for (int j = 0; j < DIM; ++j)
            U[i][j] = ca[i] * Jl[i][j] + sa[i] * Jl[d1 - i][j];     // Za @ J

    float V[DIM][DIM];
#pragma unroll
    for (int i = 0; i < DIM; ++i)
#pragma unroll
        for (int j = 0; j < DIM; ++j)
            V[i][j] = U[i][j] * cb[j] + U[i][d1 - j] * sb[d1 - j];  // (.) @ Zb

    float W[DIM][DIM];
#pragma unroll
    for (int i = 0; i < DIM; ++i)
#pragma unroll
        for (int j = 0; j < DIM; ++j) {
            float acc = 0.f;
#pragma unroll
            for (int k = 0; k < DIM; ++k)
                acc = fmaf(V[i][k], Jl[k][j], acc);                 // (.) @ J
            W[i][j] = acc;
        }
#pragma unroll
    for (int i = 0; i < DIM; ++i)
#pragma unroll
        for (int j = 0; j < DIM; ++j)
            D[i][j] = W[i][j] * cc[j] + W[i][d1 - j] * sc[d1 - j];  // (.) @ Zc
}

// to_m is the reference's deterministic _build_to_m() permutation:
// order = [0,2,6,3,7,1,5,8,4];  wm[m][:] = W[order[m]][:];  wm_inv = wm^T.
// W rows: W[0]=e0; W[1+r] has D1[r] at cols 1..3; W[4+r] has D2[r] at cols 4..8.
// => wm rows (m=0..8) come from: e0, D1r1, D2r2, D1r2, D2r3, D1r0, D2r1, D2r4, D2r0.

__global__ __launch_bounds__(TPB) void wigner_kernel(
    const float* __restrict__ vec, const float* __restrict__ rnd,
    const float* __restrict__ J1,  const float* __restrict__ J2,
    float* __restrict__ outR,
    float* __restrict__ outWm,
    float* __restrict__ outWi,
    int E)
{
    __shared__ __align__(16) float ldsR[TPB * 9];
    __shared__ __align__(16) float ldsW[TPB * 81];

    const int t  = threadIdx.x;
    const int e0 = blockIdx.x * TPB;
    const int e  = e0 + t;
    const int ei = (e < E) ? e : (E - 1);
    const int nvalid = min(TPB, E - e0);

    // ---------------- per-edge math (f32, no transcendentals) ----------------
    float vx = vec[3 * ei + 0], vy = vec[3 * ei + 1], vz = vec[3 * ei + 2];
    float rn = rsqrtf(vx * vx + vy * vy + vz * vz);
    float nx0 = vx * rn, nx1 = vy * rn, nx2 = vz * rn;     // norm_x

    float ox = rnd[3 * ei + 0] - 0.5f;
    float oy = rnd[3 * ei + 1] - 0.5f;
    float oz = rnd[3 * ei + 2] - 0.5f;
    float ro = rsqrtf(ox * ox + oy * oy + oz * oz);
    ox *= ro; oy *= ro; oz *= ro;                          // original e2

    // candidate selection (e2b, e2c from ORIGINAL e2)
    float sx = ox, sy = oy, sz = oz;
    float dcur = fabsf(sx * nx0 + sy * nx1 + sz * nx2);
    {
        float bx = -oy, by = ox, bz = oz;
        float db = fabsf(bx * nx0 + by * nx1 + bz * nx2);
        if (dcur > db) { sx = bx; sy = by; sz = bz; dcur = db; }
        float cx = ox, cy = -oz, cz = oy;
        float dc = fabsf(cx * nx0 + cy * nx1 + cz * nx2);
        if (dcur > dc) { sx = cx; sy = cy; sz = cz; }
    }

    // norm_z = normalize(cross(norm_x, e2))
    float zx = nx1 * sz - nx2 * sy;
    float zy = nx2 * sx - nx0 * sz;
    float zz = nx0 * sy - nx1 * sx;
    float rz = rsqrtf(zx * zx + zy * zy + zz * zz);
    zx *= rz; zy *= rz; zz *= rz;

    // norm_y = normalize(cross(norm_x, norm_z))
    float yx = nx1 * zz - nx2 * zy;
    float yy = nx2 * zx - nx0 * zz;
    float yz = nx0 * zy - nx1 * zx;
    float ry = rsqrtf(yx * yx + yy * yy + yz * yz);
    yx *= ry; yy *= ry; yz *= ry;

    // ---- sin/cos of Euler angles, algebraically (no atan2/acos/sincos) ----
    // alpha = atan2(zy, yy):
    float h2a = zy * zy + yy * yy;
    float rha = rsqrtf(fmaxf(h2a, 1e-30f));
    bool  za  = (h2a < 1e-24f);
    float sa  = za ? 0.f : zy * rha;
    float caa = za ? 1.f : yy * rha;
    // beta = acos(clip(nx1)):  cos b = clip(nx1), sin b = sqrt(1-c^2) >= 0
    float cbb = fminf(1.f, fmaxf(-1.f, nx1));
    float sb  = sqrtf(fmaxf(0.f, 1.f - cbb * cbb));
    // gamma = atan2(caa*zz - sa*yz, caa*zx - sa*yx):
    float gy  = caa * zz - sa * yz;
    float gx  = caa * zx - sa * yx;
    float h2g = gy * gy + gx * gx;
    float rhg = rsqrtf(fmaxf(h2g, 1e-30f));
    bool  zg  = (h2g < 1e-24f);
    float sg  = zg ? 0.f : gy * rhg;
    float cgg = zg ? 1.f : gx * rhg;

    // l = 1 block
    float ca3[3] = {caa, 1.f, caa}, sa3[3] = {sa, 0.f, -sa};
    float cb3[3] = {cbb, 1.f, cbb}, sb3[3] = {sb, 0.f, -sb};
    float cc3[3] = {cgg, 1.f, cgg}, sc3[3] = {sg, 0.f, -sg};
    float D1[3][3];
    zchain<3>(J1, ca3, sa3, cb3, sb3, cc3, sc3, D1);

    // l = 2 block (double angles via identities)
    float ca2 = caa * caa - sa * sa,  sa2 = 2.f * sa * caa;
    float cb2 = cbb * cbb - sb * sb,  sb2 = 2.f * sb * cbb;
    float cg2 = cgg * cgg - sg * sg,  sg2 = 2.f * sg * cgg;
    float ca5[5] = {ca2, caa, 1.f, caa, ca2}, sa5[5] = {sa2, sa, 0.f, -sa, -sa2};
    float cb5[5] = {cb2, cbb, 1.f, cbb, cb2}, sb5[5] = {sb2, sb, 0.f, -sb, -sb2};
    float cc5[5] = {cg2, cgg, 1.f, cgg, cg2}, sc5[5] = {sg2, sg, 0.f, -sg, -sg2};
    float D2[5][5];
    zchain<5>(J2, ca5, sa5, cb5, sb5, cc5, sc5, D2);

    // ---------------- build R and wm (static layout) ----------------
    {
        float* r9 = &ldsR[t * 9];
        r9[0] = zx;  r9[1] = zy;  r9[2] = zz;
        r9[3] = nx0; r9[4] = nx1; r9[5] = nx2;
        r9[6] = yx;  r9[7] = yy;  r9[8] = yz;

        float* w = &ldsW[t * 81];
        // m0: e0
        w[0] = 1.f;
#pragma unroll
        for (int c = 1; c < 9; ++c) w[c] = 0.f;
        // m1: D1 row1 @ cols1-3
        w[9]  = 0.f; w[10] = D1[1][0]; w[11] = D1[1][1]; w[12] = D1[1][2];
#pragma unroll
        for (int c = 4; c < 9; ++c) w[9 + c] = 0.f;
        // m2: D2 row2 @ cols4-8
#pragma unroll
        for (int c = 0; c < 4; ++c) w[18 + c] = 0.f;
#pragma unroll
        for (int c = 0; c < 5; ++c) w[22 + c] = D2[2][c];
        // m3: D1 row2
        w[27] = 0.f; w[28] = D1[2][0]; w[29] = D1[2][1]; w[30] = D1[2][2];
#pragma unroll
        for (int c = 4; c < 9; ++c) w[27 + c] = 0.f;
        // m4: D2 row3
#pragma unroll
        for (int c = 0; c < 4; ++c) w[36 + c] = 0.f;
#pragma unroll
        for (int c = 0; c < 5; ++c) w[40 + c] = D2[3][c];
        // m5: D1 row0
        w[45] = 0.f; w[46] = D1[0][0]; w[47] = D1[0][1]; w[48] = D1[0][2];
#pragma unroll
        for (int c = 4; c < 9; ++c) w[45 + c] = 0.f;
        // m6: D2 row1
#pragma unroll
        for (int c = 0; c < 4; ++c) w[54 + c] = 0.f;
#pragma unroll
        for (int c = 0; c < 5; ++c) w[58 + c] = D2[1][c];
        // m7: D2 row4
#pragma unroll
        for (int c = 0; c < 4; ++c) w[63 + c] = 0.f;
#pragma unroll
        for (int c = 0; c < 5; ++c) w[67 + c] = D2[4][c];
        // m8: D2 row0
#pragma unroll
        for (int c = 0; c < 4; ++c) w[72 + c] = 0.f;
#pragma unroll
        for (int c = 0; c < 5; ++c) w[76 + c] = D2[0][c];
    }
    __syncthreads();

    // ---------------- copy-out R and wm (coalesced float4, nontemporal) ----------------
    if (nvalid == TPB) {
        const f32x4* sR = reinterpret_cast<const f32x4*>(ldsR);
        f32x4* dR = reinterpret_cast<f32x4*>(outR + (size_t)e0 * 9);
#pragma unroll
        for (int idx = t; idx < (TPB * 9) / 4; idx += TPB)
            __builtin_nontemporal_store(sR[idx], &dR[idx]);
        const f32x4* sW = reinterpret_cast<const f32x4*>(ldsW);
        f32x4* dW = reinterpret_cast<f32x4*>(outWm + (size_t)e0 * 81);
        for (int idx = t; idx < (TPB * 81) / 4; idx += TPB)
            __builtin_nontemporal_store(sW[idx], &dW[idx]);
    } else {
        float* dR = outR + (size_t)e0 * 9;
        for (int idx = t; idx < nvalid * 9; idx += TPB) dR[idx] = ldsR[idx];
        float* dW = outWm + (size_t)e0 * 81;
        for (int idx = t; idx < nvalid * 81; idx += TPB) dW[idx] = ldsW[idx];
    }
    __syncthreads();

    // ---------------- build wm_inv = wm^T (static layout) ----------------
    {
        float* w = &ldsW[t * 81];
        // row0
        w[0] = 1.f;
#pragma unroll
        for (int c = 1; c < 9; ++c) w[c] = 0.f;
        // rows 1..3: [0, D1[1][j], 0, D1[2][j], 0, D1[0][j], 0, 0, 0] for j=row-1
#pragma unroll
        for (int j = 0; j < 3; ++j) {
            float* r = &w[(1 + j) * 9];
            r[0] = 0.f; r[1] = D1[1][j]; r[2] = 0.f; r[3] = D1[2][j];
            r[4] = 0.f; r[5] = D1[0][j]; r[6] = 0.f; r[7] = 0.f; r[8] = 0.f;
        }
        // rows 4..8: [0, 0, D2[2][c], 0, D2[3][c], 0, D2[1][c], D2[4][c], D2[0][c]]
#pragma unroll
        for (int c = 0; c < 5; ++c) {
            float* r = &w[(4 + c) * 9];
            r[0] = 0.f; r[1] = 0.f; r[2] = D2[2][c]; r[3] = 0.f;
            r[4] = D2[3][c]; r[5] = 0.f; r[6] = D2[1][c];
            r[7] = D2[4][c]; r[8] = D2[0][c];
        }
    }
    __syncthreads();

    // ---------------- copy-out wm_inv ----------------
    if (nvalid == TPB) {
        const f32x4* sW = reinterpret_cast<const f32x4*>(ldsW);
        f32x4* dW = reinterpret_cast<f32x4*>(outWi + (size_t)e0 * 81);
        for (int idx = t; idx < (TPB * 81) / 4; idx += TPB)
            __builtin_nontemporal_store(sW[idx], &dW[idx]);
    } else {
        float* dW = outWi + (size_t)e0 * 81;
        for (int idx = t; idx < nvalid * 81; idx += TPB) dW[idx] = ldsW[idx];
    }
}

extern "C" void kernel_launch(void* const* d_in, const int* in_sizes, int n_in,
                              void* d_out, int out_size, void* d_ws, size_t ws_size,
                              hipStream_t stream) {
    const float* vec = (const float*)d_in[0];
    const float* rnd = (const float*)d_in[1];
    const float* J1  = (const float*)d_in[2];
    const float* J2  = (const float*)d_in[3];
    float* out = (float*)d_out;

    const int E = in_sizes[0] / 3;
    float* outR  = out;
    float* outWm = out + (size_t)E * 9;
    float* outWi = out + (size_t)E * 90;

    const int blocks = (E + TPB - 1) / TPB;
    hipLaunchKernelGGL(wigner_kernel, dim3(blocks), dim3(TPB), 0, stream,
                       vec, rnd, J1, J2, outR, outWm, outWi, E);
}

// Round 6
// 108.222 us; speedup vs baseline: 1.0924x; 1.0012x over previous
//
#include <hip/hip_runtime.h>
#include <hip/hip_bf16.h>
#include <math.h>

#define TPB 64

typedef float f32x4 __attribute__((ext_vector_type(4)));

// Wave-local LDS fence: workgroup == 1 wave, so cross-lane LDS visibility only
// needs lgkmcnt(0) — NOT the vmcnt(0) drain that __syncthreads() would force.
// sched_barrier(0) on both sides keeps the compiler from hoisting LDS ops past it.
__device__ __forceinline__ void wave_lds_fence() {
    __builtin_amdgcn_sched_barrier(0);
    asm volatile("s_waitcnt lgkmcnt(0)" ::: "memory");
    __builtin_amdgcn_sched_barrier(0);
}

// D = Za @ J @ Zb @ J @ Zc  (reference z-rot structure: Z[i][i]=cs[i], Z[i][DIM-1-i]=sn[i])
template<int DIM>
__device__ __forceinline__ void zchain(
    const float* __restrict__ J,
    const float (&ca)[DIM], const float (&sa)[DIM],
    const float (&cb)[DIM], const float (&sb)[DIM],
    const float (&cc)[DIM], const float (&sc)[DIM],
    float (&D)[DIM][DIM])
{
    constexpr int d1 = DIM - 1;
    float Jl[DIM][DIM];
#pragma unroll
    for (int i = 0; i < DIM; ++i)
#pragma unroll
        for (int j = 0; j < DIM; ++j)
            Jl[i][j] = J[i * DIM + j];   // uniform -> scalar loads

    float U[DIM][DIM];
#pragma unroll
    for (int i = 0; i < DIM; ++i)
#pragma unroll
        for (int j = 0; j < DIM; ++j)
            U[i][j] = ca[i] * Jl[i][j] + sa[i] * Jl[d1 - i][j];     // Za @ J

    float V[DIM][DIM];
#pragma unroll
    for (int i = 0; i < DIM; ++i)
#pragma unroll
        for (int j = 0; j < DIM; ++j)
            V[i][j] = U[i][j] * cb[j] + U[i][d1 - j] * sb[d1 - j];  // (.) @ Zb

    float W[DIM][DIM];
#pragma unroll
    for (int i = 0; i < DIM; ++i)
#pragma unroll
        for (int j = 0; j < DIM; ++j) {
            float acc = 0.f;
#pragma unroll
            for (int k = 0; k < DIM; ++k)
                acc = fmaf(V[i][k], Jl[k][j], acc);                 // (.) @ J
            W[i][j] = acc;
        }
#pragma unroll
    for (int i = 0; i < DIM; ++i)
#pragma unroll
        for (int j = 0; j < DIM; ++j)
            D[i][j] = W[i][j] * cc[j] + W[i][d1 - j] * sc[d1 - j];  // (.) @ Zc
}

// to_m is the reference's deterministic _build_to_m() permutation:
// order = [0,2,6,3,7,1,5,8,4];  wm[m][:] = W[order[m]][:];  wm_inv = wm^T.
// => wm rows (m=0..8) come from: e0, D1r1, D2r2, D1r2, D2r3, D1r0, D2r1, D2r4, D2r0.

__global__ __launch_bounds__(TPB) void wigner_kernel(
    const float* __restrict__ vec, const float* __restrict__ rnd,
    const float* __restrict__ J1,  const float* __restrict__ J2,
    float* __restrict__ outR,
    float* __restrict__ outWm,
    float* __restrict__ outWi,
    int E)
{
    __shared__ __align__(16) float ldsR[TPB * 9];
    __shared__ __align__(16) float ldsW[TPB * 81];

    const int t  = threadIdx.x;
    const int e0 = blockIdx.x * TPB;
    const int e  = e0 + t;
    const int ei = (e < E) ? e : (E - 1);
    const int nvalid = min(TPB, E - e0);

    // ---------------- per-edge math (f32, no transcendentals) ----------------
    float vx = vec[3 * ei + 0], vy = vec[3 * ei + 1], vz = vec[3 * ei + 2];
    float rn = rsqrtf(vx * vx + vy * vy + vz * vz);
    float nx0 = vx * rn, nx1 = vy * rn, nx2 = vz * rn;     // norm_x

    float ox = rnd[3 * ei + 0] - 0.5f;
    float oy = rnd[3 * ei + 1] - 0.5f;
    float oz = rnd[3 * ei + 2] - 0.5f;
    float ro = rsqrtf(ox * ox + oy * oy + oz * oz);
    ox *= ro; oy *= ro; oz *= ro;                          // original e2

    // candidate selection (e2b, e2c from ORIGINAL e2)
    float sx = ox, sy = oy, sz = oz;
    float dcur = fabsf(sx * nx0 + sy * nx1 + sz * nx2);
    {
        float bx = -oy, by = ox, bz = oz;
        float db = fabsf(bx * nx0 + by * nx1 + bz * nx2);
        if (dcur > db) { sx = bx; sy = by; sz = bz; dcur = db; }
        float cx = ox, cy = -oz, cz = oy;
        float dc = fabsf(cx * nx0 + cy * nx1 + cz * nx2);
        if (dcur > dc) { sx = cx; sy = cy; sz = cz; }
    }

    // norm_z = normalize(cross(norm_x, e2))
    float zx = nx1 * sz - nx2 * sy;
    float zy = nx2 * sx - nx0 * sz;
    float zz = nx0 * sy - nx1 * sx;
    float rz = rsqrtf(zx * zx + zy * zy + zz * zz);
    zx *= rz; zy *= rz; zz *= rz;

    // norm_y = normalize(cross(norm_x, norm_z))
    float yx = nx1 * zz - nx2 * zy;
    float yy = nx2 * zx - nx0 * zz;
    float yz = nx0 * zy - nx1 * zx;
    float ry = rsqrtf(yx * yx + yy * yy + yz * yz);
    yx *= ry; yy *= ry; yz *= ry;

    // ---- sin/cos of Euler angles, algebraically (no atan2/acos/sincos) ----
    float h2a = zy * zy + yy * yy;
    float rha = rsqrtf(fmaxf(h2a, 1e-30f));
    bool  za  = (h2a < 1e-24f);
    float sa  = za ? 0.f : zy * rha;
    float caa = za ? 1.f : yy * rha;
    float cbb = fminf(1.f, fmaxf(-1.f, nx1));
    float sb  = sqrtf(fmaxf(0.f, 1.f - cbb * cbb));
    float gy  = caa * zz - sa * yz;
    float gx  = caa * zx - sa * yx;
    float h2g = gy * gy + gx * gx;
    float rhg = rsqrtf(fmaxf(h2g, 1e-30f));
    bool  zg  = (h2g < 1e-24f);
    float sg  = zg ? 0.f : gy * rhg;
    float cgg = zg ? 1.f : gx * rhg;

    // l = 1 block
    float ca3[3] = {caa, 1.f, caa}, sa3[3] = {sa, 0.f, -sa};
    float cb3[3] = {cbb, 1.f, cbb}, sb3[3] = {sb, 0.f, -sb};
    float cc3[3] = {cgg, 1.f, cgg}, sc3[3] = {sg, 0.f, -sg};
    float D1[3][3];
    zchain<3>(J1, ca3, sa3, cb3, sb3, cc3, sc3, D1);

    // l = 2 block (double angles via identities)
    float ca2 = caa * caa - sa * sa,  sa2 = 2.f * sa * caa;
    float cb2 = cbb * cbb - sb * sb,  sb2 = 2.f * sb * cbb;
    float cg2 = cgg * cgg - sg * sg,  sg2 = 2.f * sg * cgg;
    float ca5[5] = {ca2, caa, 1.f, caa, ca2}, sa5[5] = {sa2, sa, 0.f, -sa, -sa2};
    float cb5[5] = {cb2, cbb, 1.f, cbb, cb2}, sb5[5] = {sb2, sb, 0.f, -sb, -sb2};
    float cc5[5] = {cg2, cgg, 1.f, cgg, cg2}, sc5[5] = {sg2, sg, 0.f, -sg, -sg2};
    float D2[5][5];
    zchain<5>(J2, ca5, sa5, cb5, sb5, cc5, sc5, D2);

    // ---------------- build R and wm (static layout) ----------------
    {
        float* r9 = &ldsR[t * 9];
        r9[0] = zx;  r9[1] = zy;  r9[2] = zz;
        r9[3] = nx0; r9[4] = nx1; r9[5] = nx2;
        r9[6] = yx;  r9[7] = yy;  r9[8] = yz;

        float* w = &ldsW[t * 81];
        // m0: e0
        w[0] = 1.f;
#pragma unroll
        for (int c = 1; c < 9; ++c) w[c] = 0.f;
        // m1: D1 row1 @ cols1-3
        w[9]  = 0.f; w[10] = D1[1][0]; w[11] = D1[1][1]; w[12] = D1[1][2];
#pragma unroll
        for (int c = 4; c < 9; ++c) w[9 + c] = 0.f;
        // m2: D2 row2 @ cols4-8
#pragma unroll
        for (int c = 0; c < 4; ++c) w[18 + c] = 0.f;
#pragma unroll
        for (int c = 0; c < 5; ++c) w[22 + c] = D2[2][c];
        // m3: D1 row2
        w[27] = 0.f; w[28] = D1[2][0]; w[29] = D1[2][1]; w[30] = D1[2][2];
#pragma unroll
        for (int c = 4; c < 9; ++c) w[27 + c] = 0.f;
        // m4: D2 row3
#pragma unroll
        for (int c = 0; c < 4; ++c) w[36 + c] = 0.f;
#pragma unroll
        for (int c = 0; c < 5; ++c) w[40 + c] = D2[3][c];
        // m5: D1 row0
        w[45] = 0.f; w[46] = D1[0][0]; w[47] = D1[0][1]; w[48] = D1[0][2];
#pragma unroll
        for (int c = 4; c < 9; ++c) w[45 + c] = 0.f;
        // m6: D2 row1
#pragma unroll
        for (int c = 0; c < 4; ++c) w[54 + c] = 0.f;
#pragma unroll
        for (int c = 0; c < 5; ++c) w[58 + c] = D2[1][c];
        // m7: D2 row4
#pragma unroll
        for (int c = 0; c < 4; ++c) w[63 + c] = 0.f;
#pragma unroll
        for (int c = 0; c < 5; ++c) w[67 + c] = D2[4][c];
        // m8: D2 row0
#pragma unroll
        for (int c = 0; c < 4; ++c) w[72 + c] = 0.f;
#pragma unroll
        for (int c = 0; c < 5; ++c) w[76 + c] = D2[0][c];
    }
    wave_lds_fence();   // 1-wave workgroup: lgkmcnt(0) suffices, no vmcnt drain

    // ---------------- copy-out R and wm (coalesced float4, nontemporal) ----------------
    if (nvalid == TPB) {
        const f32x4* sR = reinterpret_cast<const f32x4*>(ldsR);
        f32x4* dR = reinterpret_cast<f32x4*>(outR + (size_t)e0 * 9);
#pragma unroll
        for (int idx = t; idx < (TPB * 9) / 4; idx += TPB)
            __builtin_nontemporal_store(sR[idx], &dR[idx]);
        const f32x4* sW = reinterpret_cast<const f32x4*>(ldsW);
        f32x4* dW = reinterpret_cast<f32x4*>(outWm + (size_t)e0 * 81);
        for (int idx = t; idx < (TPB * 81) / 4; idx += TPB)
            __builtin_nontemporal_store(sW[idx], &dW[idx]);
    } else {
        float* dR = outR + (size_t)e0 * 9;
        for (int idx = t; idx < nvalid * 9; idx += TPB) dR[idx] = ldsR[idx];
        float* dW = outWm + (size_t)e0 * 81;
        for (int idx = t; idx < nvalid * 81; idx += TPB) dW[idx] = ldsW[idx];
    }
    wave_lds_fence();   // ds_reads above complete before ldsW is overwritten

    // ---------------- build wm_inv = wm^T (static layout) ----------------
    {
        float* w = &ldsW[t * 81];
        // row0
        w[0] = 1.f;
#pragma unroll
        for (int c = 1; c < 9; ++c) w[c] = 0.f;
        // rows 1..3: [0, D1[1][j], 0, D1[2][j], 0, D1[0][j], 0, 0, 0] for j=row-1
#pragma unroll
        for (int j = 0; j < 3; ++j) {
            float* r = &w[(1 + j) * 9];
            r[0] = 0.f; r[1] = D1[1][j]; r[2] = 0.f; r[3] = D1[2][j];
            r[4] = 0.f; r[5] = D1[0][j]; r[6] = 0.f; r[7] = 0.f; r[8] = 0.f;
        }
        // rows 4..8: [0, 0, D2[2][c], 0, D2[3][c], 0, D2[1][c], D2[4][c], D2[0][c]]
#pragma unroll
        for (int c = 0; c < 5; ++c) {
            float* r = &w[(4 + c) * 9];
            r[0] = 0.f; r[1] = 0.f; r[2] = D2[2][c]; r[3] = 0.f;
            r[4] = D2[3][c]; r[5] = 0.f; r[6] = D2[1][c];
            r[7] = D2[4][c]; r[8] = D2[0][c];
        }
    }
    wave_lds_fence();

    // ---------------- copy-out wm_inv ----------------
    if (nvalid == TPB) {
        const f32x4* sW = reinterpret_cast<const f32x4*>(ldsW);
        f32x4* dW = reinterpret_cast<f32x4*>(outWi + (size_t)e0 * 81);
        for (int idx = t; idx < (TPB * 81) / 4; idx += TPB)
            __builtin_nontemporal_store(sW[idx], &dW[idx]);
    } else {
        float* dW = outWi + (size_t)e0 * 81;
        for (int idx = t; idx < nvalid * 81; idx += TPB) dW[idx] = ldsW[idx];
    }
}

extern "C" void kernel_launch(void* const* d_in, const int* in_sizes, int n_in,
                              void* d_out, int out_size, void* d_ws, size_t ws_size,
                              hipStream_t stream) {
    const float* vec = (const float*)d_in[0];
    const float* rnd = (const float*)d_in[1];
    const float* J1  = (const float*)d_in[2];
    const float* J2  = (const float*)d_in[3];
    float* out = (float*)d_out;

    const int E = in_sizes[0] / 3;
    float* outR  = out;
    float* outWm = out + (size_t)E * 9;
    float* outWi = out + (size_t)E * 90;

    const int blocks = (E + TPB - 1) / TPB;
    hipLaunchKernelGGL(wigner_kernel, dim3(blocks), dim3(TPB), 0, stream,
                       vec, rnd, J1, J2, outR, outWm, outWi, E);
}